// Round 4
// baseline (980.770 us; speedup 1.0000x reference)
//
#include <hip/hip_runtime.h>

typedef _Float16 h8 __attribute__((ext_vector_type(8)));
typedef float f4 __attribute__((ext_vector_type(4)));
typedef float f16v __attribute__((ext_vector_type(16)));

#define MFMA16(a, b, c) __builtin_amdgcn_mfma_f32_16x16x32_f16((a), (b), (c), 0, 0, 0)
#define MFMA32(a, b, c) __builtin_amdgcn_mfma_f32_32x32x16_f16((a), (b), (c), 0, 0, 0)

// B=4, S=4096, D_IN=D_OUT=512
//
// Image layouts (fragment loads become lane-contiguous global_load_dwordx4):
//  Q/K img: elem (b,s,d) at ((b*64 + (d>>3))*4096 + s)*8 + (d&7)   [16 MB each]
//  V   img: elem (b,s,d) at ((b*512 + (s>>3))*512 + d)*8 + (s&7)   [16 MB]

// ---------------- weight convert: Wt[z][n][k] = W_z[k][n] * (z==0 ? 0.5 : 1) ----------------
__global__ void wconv_kernel(const float* __restrict__ Wq, const float* __restrict__ Wk,
                             const float* __restrict__ Wv, _Float16* __restrict__ Wt) {
  int idx = blockIdx.x * 256 + threadIdx.x;
  int z = idx >> 15;
  int rem = idx & 32767;
  int n = rem >> 6;
  int k0 = (rem & 63) << 3;
  const float* W = (z == 0) ? Wq : (z == 1) ? Wk : Wv;
  float sc = (z == 0) ? 0.5f : 1.0f;
  h8 v;
#pragma unroll
  for (int j = 0; j < 8; ++j) v[j] = (_Float16)(W[(k0 + j) * 512 + n] * sc);
  *(h8*)&Wt[(size_t)z * 262144 + n * 512 + k0] = v;
}

// ---------------- QKV projection -> images ----------------
__global__ __launch_bounds__(256, 2)
void proj_kernel(const float* __restrict__ x, const _Float16* __restrict__ Wt,
                 const float* __restrict__ bq, const float* __restrict__ bk,
                 const float* __restrict__ bv,
                 _Float16* __restrict__ Qimg, _Float16* __restrict__ Kimg,
                 _Float16* __restrict__ Vimg) {
  __shared__ _Float16 sMem[18432];  // sA|sB in main loop; sC (128x136) in epilogue
  _Float16* sA = sMem;
  _Float16* sB = sMem + 9216;
  const int tid = threadIdx.x;
  const int wave = tid >> 6, lane = tid & 63;
  const int quad = lane >> 4, lr = lane & 15;
  const int mbase = blockIdx.x * 128;
  const int nbase = blockIdx.y * 128;
  const int z = blockIdx.z;
  const _Float16* W = Wt + (size_t)z * 262144;

  const int sr = tid >> 1;
  const int sseg = tid & 1;
  const int rbase = (wave & 1) * 64;
  const int cbase = (wave >> 1) * 64;

  float4 ax[8];
  int4 bx[4];

  f4 acc[4][4];
#pragma unroll
  for (int i = 0; i < 4; ++i)
#pragma unroll
    for (int j = 0; j < 4; ++j) {
      f4 zz = {0.f, 0.f, 0.f, 0.f};
      acc[i][j] = zz;
    }

  {
    const float4* asrc = (const float4*)&x[(size_t)(mbase + sr) * 512 + sseg * 32];
#pragma unroll
    for (int i = 0; i < 8; ++i) ax[i] = asrc[i];
    const int4* bsrc = (const int4*)&W[(size_t)(nbase + sr) * 512 + sseg * 32];
#pragma unroll
    for (int i = 0; i < 4; ++i) bx[i] = bsrc[i];
  }

  for (int kt = 0; kt < 8; ++kt) {
    if (kt > 0) __syncthreads();
#pragma unroll
    for (int i = 0; i < 4; ++i) {
      h8 v;
      float4 f0 = ax[2 * i], f1 = ax[2 * i + 1];
      v[0] = (_Float16)f0.x; v[1] = (_Float16)f0.y; v[2] = (_Float16)f0.z; v[3] = (_Float16)f0.w;
      v[4] = (_Float16)f1.x; v[5] = (_Float16)f1.y; v[6] = (_Float16)f1.z; v[7] = (_Float16)f1.w;
      *(h8*)&sA[sr * 72 + sseg * 32 + i * 8] = v;
    }
#pragma unroll
    for (int i = 0; i < 4; ++i) *(int4*)&sB[sr * 72 + sseg * 32 + i * 8] = bx[i];
    __syncthreads();
    if (kt + 1 < 8) {
      const float4* asrc = (const float4*)&x[(size_t)(mbase + sr) * 512 + (kt + 1) * 64 + sseg * 32];
#pragma unroll
      for (int i = 0; i < 8; ++i) ax[i] = asrc[i];
      const int4* bsrc = (const int4*)&W[(size_t)(nbase + sr) * 512 + (kt + 1) * 64 + sseg * 32];
#pragma unroll
      for (int i = 0; i < 4; ++i) bx[i] = bsrc[i];
    }
#pragma unroll
    for (int ks = 0; ks < 2; ++ks) {
      h8 a[4], bb[4];
#pragma unroll
      for (int rt = 0; rt < 4; ++rt)
        a[rt] = *(const h8*)&sA[(rbase + rt * 16 + lr) * 72 + ks * 32 + quad * 8];
#pragma unroll
      for (int ct = 0; ct < 4; ++ct)
        bb[ct] = *(const h8*)&sB[(cbase + ct * 16 + lr) * 72 + ks * 32 + quad * 8];
#pragma unroll
      for (int rt = 0; rt < 4; ++rt)
#pragma unroll
        for (int ct = 0; ct < 4; ++ct)
          acc[rt][ct] = MFMA16(a[rt], bb[ct], acc[rt][ct]);
    }
  }

  // ---- epilogue: stash fp16 tile in LDS, then coalesced 16B stores to images ----
  const float* bias = (z == 0) ? bq : (z == 1) ? bk : bv;
  const float bscale = (z == 0) ? 0.5f : 1.0f;
  _Float16* sC = sMem;  // 128 x 136
  __syncthreads();
#pragma unroll
  for (int ct = 0; ct < 4; ++ct) {
    const int coll = cbase + ct * 16 + lr;
    const float bb = bias[nbase + coll] * bscale;
#pragma unroll
    for (int rt = 0; rt < 4; ++rt) {
      const int rowl = rbase + rt * 16 + quad * 4;
      if (z == 2) {  // transposed stash: sC[d_local][s_local]
#pragma unroll
        for (int r = 0; r < 4; ++r)
          sC[coll * 136 + rowl + r] = (_Float16)(acc[rt][ct][r] + bb);
      } else {       // row-major stash: sC[s_local][d_local]
#pragma unroll
        for (int r = 0; r < 4; ++r)
          sC[(rowl + r) * 136 + coll] = (_Float16)(acc[rt][ct][r] + bb);
      }
    }
  }
  __syncthreads();

  const int trow = tid >> 1, thalf = tid & 1;
  if (z != 2) {
    _Float16* img = (z == 0) ? Qimg : Kimg;
    const int sg = mbase + trow;
    const int b_ = sg >> 12, s = sg & 4095;
#pragma unroll
    for (int k = 0; k < 8; ++k) {
      const int c = thalf * 8 + k;
      const int dO = (nbase >> 3) + c;
      *(int4*)&img[(((size_t)b_ * 64 + dO) * 4096 + s) * 8] = *(const int4*)&sC[trow * 136 + c * 8];
    }
  } else {
    const int d = nbase + trow;
#pragma unroll
    for (int k = 0; k < 8; ++k) {
      const int sloc = (thalf * 8 + k) * 8;
      const int sg = mbase + sloc;
      const int b_ = sg >> 12, s4 = sg & 4095;
      *(int4*)&Vimg[(((size_t)b_ * 512 + (s4 >> 3)) * 512 + d) * 8] =
          *(const int4*)&sC[trow * 136 + sloc];
    }
  }
}

// ---------------- fused flash attention (direct-streaming, barrier-light) ----------------
// WG = 32 Q-rows, 4 waves. QK: wave cg = 32-key slice (no dup); PV: wave cg = 128-d slice
// (no dup). K/V B-frags loaded straight global->VGPR (coalesced 16B/lane); compiler emits
// fine-grained vmcnt(N) interleaved with MFMA — no staging barriers at all.
// Q: d 0..255 pinned in regs (qf[16]); d 256..511 streamed per step (L2-resident, 16KB/WG).
// Barriers: 4/step, all tiny-LDS softmax traffic. 512 WGs, 2 WGs/CU.
__global__ __launch_bounds__(256, 2)
void attn_kernel(const _Float16* __restrict__ Qimg, const _Float16* __restrict__ Kimg,
                 const _Float16* __restrict__ Vimg, float* __restrict__ out) {
  __shared__ _Float16 sP[32 * 128];  // XOR-16 swizzled
  __shared__ float sRedM[4][32], sRedS[4][32];
  __shared__ float sM[32], sL[32], sAl[32];

  const int tid = threadIdx.x;
  const int wave = tid >> 6, lane = tid & 63;
  const int l31 = lane & 31, l5 = lane >> 5;
  const int cg = wave;  // 0..3

  const int w = blockIdx.x;                  // xcd = w&7 -> batch = (w&7)>>1
  const int b = (w & 7) >> 1;
  const int qt = ((w >> 3) << 1) | (w & 1);  // 0..127
  const int qbase = qt * 32;

  const _Float16* Qb = Qimg + (size_t)b * 2097152;
  const _Float16* Kb = Kimg + (size_t)b * 2097152;
  const _Float16* Vb = Vimg + (size_t)b * 2097152;

  if (tid < 32) { sM[tid] = -3.0e38f; sL[tid] = 0.f; }

  // Q A-frags, lower 256 d: row = l31, k-octet = kc*2 + l5
  h8 qf[16];
#pragma unroll
  for (int kc = 0; kc < 16; ++kc)
    qf[kc] = *(const h8*)&Qb[(((size_t)(kc * 2 + l5)) * 4096 + qbase + l31) * 8];

  f16v O[4];
#pragma unroll
  for (int ct = 0; ct < 4; ++ct)
#pragma unroll
    for (int i = 0; i < 16; ++i) O[ct][i] = 0.f;

  for (int step = 0; step < 32; ++step) {
    const int kb = step << 7;
    const int keyg = kb + cg * 32 + l31;  // this wave's QK key column

    f16v S;
#pragma unroll
    for (int i = 0; i < 16; ++i) S[i] = 0.f;

    // ---- QK: d 0..255 from pinned Q frags ----
#pragma unroll
    for (int kc = 0; kc < 16; ++kc) {
      h8 bf = *(const h8*)&Kb[(((size_t)(kc * 2 + l5)) * 4096 + keyg) * 8];
      S = MFMA32(qf[kc], bf, S);
    }
    // ---- QK: d 256..511, Q streamed (L2-hot) ----
#pragma unroll
    for (int kc = 16; kc < 32; ++kc) {
      h8 af = *(const h8*)&Qb[(((size_t)(kc * 2 + l5)) * 4096 + qbase + l31) * 8];
      h8 bf = *(const h8*)&Kb[(((size_t)(kc * 2 + l5)) * 4096 + keyg) * 8];
      S = MFMA32(af, bf, S);
    }

    // ---- online softmax over this step's 128 keys ----
    float m[16];
#pragma unroll
    for (int i = 0; i < 16; ++i) m[i] = S[i];
#pragma unroll
    for (int i = 0; i < 16; ++i) {
      m[i] = fmaxf(m[i], __shfl_xor(m[i], 1));
      m[i] = fmaxf(m[i], __shfl_xor(m[i], 2));
      m[i] = fmaxf(m[i], __shfl_xor(m[i], 4));
      m[i] = fmaxf(m[i], __shfl_xor(m[i], 8));
      m[i] = fmaxf(m[i], __shfl_xor(m[i], 16));
    }
#pragma unroll
    for (int i = 0; i < 16; ++i)
      if (l31 == i) sRedM[cg][(i & 3) + 8 * (i >> 2) + 4 * l5] = m[i];
    __syncthreads();  // bar1

    if (tid < 32) {
      const float mo = sM[tid];
      float mn = fmaxf(fmaxf(sRedM[0][tid], sRedM[1][tid]),
                       fmaxf(sRedM[2][tid], sRedM[3][tid]));
      mn = fmaxf(mn, mo);
      sAl[tid] = __expf(mo - mn);
      sM[tid] = mn;
    }
    __syncthreads();  // bar2

    {
      f4 mq[4];
#pragma unroll
      for (int g2 = 0; g2 < 4; ++g2) mq[g2] = *(const f4*)&sM[g2 * 8 + l5 * 4];
#pragma unroll
      for (int i = 0; i < 16; ++i) S[i] = __expf(S[i] - mq[i >> 2][i & 3]);
      // P -> sP (fp16, XOR-16 chunk swizzle); col = this wave's 32 keys
      const int ck = cg * 4 + (l31 >> 3), ke = l31 & 7;
#pragma unroll
      for (int i = 0; i < 16; ++i) {
        const int row = (i & 3) + 8 * (i >> 2) + 4 * l5;
        sP[row * 128 + ((ck ^ (row & 15)) << 3) + ke] = (_Float16)S[i];
      }
      // row sums (destroys S)
#pragma unroll
      for (int i = 0; i < 16; ++i) {
        S[i] += __shfl_xor(S[i], 1);
        S[i] += __shfl_xor(S[i], 2);
        S[i] += __shfl_xor(S[i], 4);
        S[i] += __shfl_xor(S[i], 8);
        S[i] += __shfl_xor(S[i], 16);
      }
#pragma unroll
      for (int i = 0; i < 16; ++i)
        if (l31 == i) sRedS[cg][(i & 3) + 8 * (i >> 2) + 4 * l5] = S[i];
      // O rescale by alpha
      f4 aq[4];
#pragma unroll
      for (int g2 = 0; g2 < 4; ++g2) aq[g2] = *(const f4*)&sAl[g2 * 8 + l5 * 4];
#pragma unroll
      for (int ct = 0; ct < 4; ++ct)
#pragma unroll
        for (int i = 0; i < 16; ++i) O[ct][i] *= aq[i >> 2][i & 3];
    }
    __syncthreads();  // bar3: P + sRedS visible

    if (tid < 32) {
      sL[tid] = sL[tid] * sAl[tid] +
                (sRedS[0][tid] + sRedS[1][tid] + sRedS[2][tid] + sRedS[3][tid]);
    }

    // ---- PV: this wave's 128-d slice, all 128 keys, V direct from global ----
    {
      h8 pf[8];
#pragma unroll
      for (int kc2 = 0; kc2 < 8; ++kc2)
        pf[kc2] = *(const h8*)&sP[l31 * 128 + (((kc2 * 2 + l5) ^ (l31 & 15)) << 3)];
      const int kO = kb >> 3;
#pragma unroll
      for (int kc2 = 0; kc2 < 8; ++kc2) {
#pragma unroll
        for (int ct = 0; ct < 4; ++ct) {
          const int d = cg * 128 + ct * 32 + l31;
          h8 vf = *(const h8*)&Vb[(((size_t)(kO + kc2 * 2 + l5)) * 512 + d) * 8];
          O[ct] = MFMA32(pf[kc2], vf, O[ct]);
        }
      }
    }
    __syncthreads();  // bar4: sP/sRed reusable next step
  }

  // ---- epilogue: O / l ----
  f4 lq[4];
#pragma unroll
  for (int g2 = 0; g2 < 4; ++g2) lq[g2] = *(const f4*)&sL[g2 * 8 + l5 * 4];
#pragma unroll
  for (int ct = 0; ct < 4; ++ct) {
    const int col = cg * 128 + ct * 32 + l31;
#pragma unroll
    for (int i = 0; i < 16; ++i) {
      const float inv = 1.0f / lq[i >> 2][i & 3];
      const int row = qbase + (i & 3) + 8 * (i >> 2) + 4 * l5;
      out[((size_t)b * 4096 + row) * 512 + col] = O[ct][i] * inv;
    }
  }
}

extern "C" void kernel_launch(void* const* d_in, const int* in_sizes, int n_in,
                              void* d_out, int out_size, void* d_ws, size_t ws_size,
                              hipStream_t stream) {
  (void)in_sizes; (void)n_in; (void)out_size; (void)ws_size;
  const float* x  = (const float*)d_in[0];
  const float* Wq = (const float*)d_in[1];
  const float* bq = (const float*)d_in[2];
  const float* Wk = (const float*)d_in[3];
  const float* bk = (const float*)d_in[4];
  const float* Wv = (const float*)d_in[5];
  const float* bv = (const float*)d_in[6];
  float* out = (float*)d_out;
  char* ws = (char*)d_ws;
  // ws: Qimg [0,16M), Kimg [16M,32M), Vimg [32M,48M), Wt [48M,49.5M)
  _Float16* Qimg = (_Float16*)(ws);
  _Float16* Kimg = (_Float16*)(ws + ((size_t)16 << 20));
  _Float16* Vimg = (_Float16*)(ws + ((size_t)32 << 20));
  _Float16* Wt   = (_Float16*)(ws + ((size_t)48 << 20));

  wconv_kernel<<<dim3(384), dim3(256), 0, stream>>>(Wq, Wk, Wv, Wt);
  proj_kernel<<<dim3(128, 4, 3), dim3(256), 0, stream>>>(x, Wt, bq, bk, bv, Qimg, Kimg, Vimg);
  attn_kernel<<<dim3(512), dim3(256), 0, stream>>>(Qimg, Kimg, Vimg, out);
}

// Round 5
// 413.873 us; speedup vs baseline: 2.3697x; 2.3697x over previous
//
#include <hip/hip_runtime.h>

typedef _Float16 h8 __attribute__((ext_vector_type(8)));
typedef float f4 __attribute__((ext_vector_type(4)));

#define MFMA16(a, b, c) __builtin_amdgcn_mfma_f32_16x16x32_f16((a), (b), (c), 0, 0, 0)

__device__ static inline void gl_lds16(const void* g, void* l) {
  __builtin_amdgcn_global_load_lds((const __attribute__((address_space(1))) unsigned int*)g,
                                   (__attribute__((address_space(3))) unsigned int*)l, 16, 0, 0);
}

// B=4, S=4096, D=512.
// IMG block = 16KB = 128 rows x 64 k fp16; half-offset(r,k) = r*64 + ((((k>>3)&7)^(r&7))<<3) + (k&7).
// XOR-8 swizzle baked in global so linear global_load_lds staging yields bank-floor ds_read_b128 frags.
//  Qimg/Kimg: block(b, rb=s>>7, kc=d>>6) at ((b*32+rb)*8+kc)*16KB        [16MB each]
//  VTimg:     block(b, rb=d>>7, kc=s>>6) at ((b*4+rb)*64+kc)*16KB        [16MB]
//  Wt:        block(z, rb=n>>7, kc=k>>6) at ((z*4+rb)*8+kc)*16KB         [1.5MB]
//  Simg(chunk): block(rbL, kc=t>>6) at (rbL*64+kc)*16KB, rbL = chunk-row>>7

// ---------------- weight convert ----------------
__global__ void wconv_kernel(const float* __restrict__ Wq, const float* __restrict__ Wk,
                             const float* __restrict__ Wv, _Float16* __restrict__ Wt) {
  int idx = blockIdx.x * 256 + threadIdx.x;
  int z = idx >> 15, rem = idx & 32767;
  int n = rem >> 6, k0 = (rem & 63) << 3;
  const float* W = (z == 0) ? Wq : (z == 1) ? Wk : Wv;
  float sc = (z == 0) ? 0.5f : 1.0f;
  h8 v;
#pragma unroll
  for (int j = 0; j < 8; ++j) v[j] = (_Float16)(W[(k0 + j) * 512 + n] * sc);
  size_t blk = (size_t)((z * 4 + (n >> 7)) * 8 + (k0 >> 6));
  int off = (n & 127) * 64 + ((((k0 >> 3) & 7) ^ (n & 7)) << 3);
  *(h8*)&Wt[blk * 8192 + off] = v;
}

// ---------------- QKV projection -> images ----------------
__global__ __launch_bounds__(256, 3)
void proj_kernel(const float* __restrict__ x, const _Float16* __restrict__ Wt,
                 const float* __restrict__ bq, const float* __restrict__ bk,
                 const float* __restrict__ bv,
                 char* __restrict__ Qimg, char* __restrict__ Kimg, char* __restrict__ VTimg) {
  __shared__ _Float16 sMem[16384];  // sA 8192 + sB 8192; epilogue stash 16384
  _Float16* sA = sMem;
  _Float16* sB = sMem + 8192;
  const int tid = threadIdx.x;
  const int wave = tid >> 6, lane = tid & 63;
  const int quad = lane >> 4, lr = lane & 15;
  const int mbase = blockIdx.x * 128, nbase = blockIdx.y * 128, z = blockIdx.z;
  const int sr = tid >> 1, sseg = tid & 1;
  const int rbase = (wave & 1) * 64, cbase = (wave >> 1) * 64;
  const char* WtB = (const char*)Wt + ((size_t)(z * 4 + (nbase >> 7)) * 8) * 16384;

  float4 ax[8];
  f4 acc[4][4];
#pragma unroll
  for (int i = 0; i < 4; ++i)
#pragma unroll
    for (int j = 0; j < 4; ++j) { f4 zz = {0.f, 0.f, 0.f, 0.f}; acc[i][j] = zz; }

  {  // preload ax(0), stage B(0)
    const float4* asrc = (const float4*)&x[(size_t)(mbase + sr) * 512 + sseg * 32];
#pragma unroll
    for (int i = 0; i < 8; ++i) ax[i] = asrc[i];
#pragma unroll
    for (int j = 0; j < 4; ++j)
      gl_lds16(WtB + tid * 16 + j * 4096, (char*)sB + tid * 16 + j * 4096);
  }

  for (int kt = 0; kt < 8; ++kt) {
    if (kt > 0) __syncthreads();  // FREE: readers of kt-1 done
    // sA(kt) from ax (fp32->fp16, swizzled)
#pragma unroll
    for (int i = 0; i < 4; ++i) {
      h8 v;
      float4 f0 = ax[2 * i], f1 = ax[2 * i + 1];
      v[0] = (_Float16)f0.x; v[1] = (_Float16)f0.y; v[2] = (_Float16)f0.z; v[3] = (_Float16)f0.w;
      v[4] = (_Float16)f1.x; v[5] = (_Float16)f1.y; v[6] = (_Float16)f1.z; v[7] = (_Float16)f1.w;
      *(h8*)&sA[sr * 64 + (((sseg * 4 + i) ^ (sr & 7)) << 3)] = v;
    }
    if (kt > 0) {  // stage B(kt)
#pragma unroll
      for (int j = 0; j < 4; ++j)
        gl_lds16(WtB + kt * 16384 + tid * 16 + j * 4096, (char*)sB + tid * 16 + j * 4096);
    }
    __syncthreads();  // DRAIN
    if (kt < 7) {
      const float4* asrc = (const float4*)&x[(size_t)(mbase + sr) * 512 + (kt + 1) * 64 + sseg * 32];
#pragma unroll
      for (int i = 0; i < 8; ++i) ax[i] = asrc[i];
    }
#pragma unroll
    for (int ks = 0; ks < 2; ++ks) {
      h8 a[4], bb[4];
#pragma unroll
      for (int rt = 0; rt < 4; ++rt) {
        const int r = rbase + rt * 16 + lr;
        a[rt] = *(const h8*)&sA[r * 64 + ((((ks << 2) | quad) ^ (lr & 7)) << 3)];
      }
#pragma unroll
      for (int ct = 0; ct < 4; ++ct) {
        const int r = cbase + ct * 16 + lr;
        bb[ct] = *(const h8*)&sB[r * 64 + ((((ks << 2) | quad) ^ (lr & 7)) << 3)];
      }
#pragma unroll
      for (int rt = 0; rt < 4; ++rt)
#pragma unroll
        for (int ct = 0; ct < 4; ++ct)
          acc[rt][ct] = MFMA16(a[rt], bb[ct], acc[rt][ct]);
    }
  }

  // ---- epilogue: swizzled stash -> coalesced image stores ----
  const float* bias = (z == 0) ? bq : (z == 1) ? bk : bv;
  const float bscale = (z == 0) ? 0.5f : 1.0f;
  _Float16* sC = sMem;
  __syncthreads();
#pragma unroll
  for (int ct = 0; ct < 4; ++ct) {
    const int dl = cbase + ct * 16 + lr;
    const float bb = bias[nbase + dl] * bscale;
#pragma unroll
    for (int rt = 0; rt < 4; ++rt) {
#pragma unroll
      for (int r = 0; r < 4; ++r) {
        const int sl = rbase + rt * 16 + quad * 4 + r;
        const _Float16 val = (_Float16)(acc[rt][ct][r] + bb);
        if (z == 2) {  // VT: row=d, k=s
          sC[((sl >> 6) << 13) + dl * 64 + ((((sl >> 3) & 7) ^ (dl & 7)) << 3) + (sl & 7)] = val;
        } else {       // Q/K: row=s, k=d
          sC[((dl >> 6) << 13) + sl * 64 + ((((dl >> 3) & 7) ^ (sl & 7)) << 3) + (dl & 7)] = val;
        }
      }
    }
  }
  __syncthreads();
  const int b_ = mbase >> 12;
  char* dst;
  if (z != 2) {
    char* img = (z == 0) ? Qimg : Kimg;
    dst = img + ((size_t)((b_ * 32 + ((mbase & 4095) >> 7)) * 8 + (nbase >> 6) + (tid >> 7))) * 16384;
  } else {
    dst = VTimg + ((size_t)((b_ * 4 + (nbase >> 7)) * 64 + ((mbase & 4095) >> 6) + (tid >> 7))) * 16384;
  }
  dst += (size_t)(tid & 127) * 128;
#pragma unroll
  for (int k = 0; k < 8; ++k)
    *(int4*)(dst + k * 16) = *(const int4*)&sC[tid * 64 + k * 8];
}

// ---------------- QK GEMM: S[s][t] = Q . K^T -> Simg chunk ----------------
__global__ __launch_bounds__(256, 3)
void qk_kernel(const char* __restrict__ Qimg, const char* __restrict__ Kimg,
               char* __restrict__ S, int b0, int s0) {
  __shared__ _Float16 sMem[16384];
  _Float16* sA = sMem;
  _Float16* sB = sMem + 8192;
  const int tid = threadIdx.x;
  const int wave = tid >> 6, lane = tid & 63;
  const int quad = lane >> 4, lr = lane & 15;
  const int cb = blockIdx.x;                               // t-block 0..31
  const int rbL = blockIdx.z * gridDim.y + blockIdx.y;     // chunk row-block
  const int b = b0 + blockIdx.z;
  const int rbase = (wave & 1) * 64, cbase = (wave >> 1) * 64;
  const char* Ab = Qimg + ((size_t)((b * 32 + (s0 >> 7) + blockIdx.y) * 8)) * 16384;
  const char* Bb = Kimg + ((size_t)((b * 32 + cb) * 8)) * 16384;

  f4 acc[4][4];
#pragma unroll
  for (int i = 0; i < 4; ++i)
#pragma unroll
    for (int j = 0; j < 4; ++j) { f4 zz = {0.f, 0.f, 0.f, 0.f}; acc[i][j] = zz; }

#pragma unroll
  for (int j = 0; j < 4; ++j) {  // stage(0)
    gl_lds16(Ab + tid * 16 + j * 4096, (char*)sA + tid * 16 + j * 4096);
    gl_lds16(Bb + tid * 16 + j * 4096, (char*)sB + tid * 16 + j * 4096);
  }

  for (int kt = 0; kt < 8; ++kt) {
    __syncthreads();  // DRAIN stage(kt)
#pragma unroll
    for (int ks = 0; ks < 2; ++ks) {
      h8 a[4], bb[4];
#pragma unroll
      for (int rt = 0; rt < 4; ++rt) {
        const int r = rbase + rt * 16 + lr;
        a[rt] = *(const h8*)&sA[r * 64 + ((((ks << 2) | quad) ^ (lr & 7)) << 3)];
      }
#pragma unroll
      for (int ct = 0; ct < 4; ++ct) {
        const int r = cbase + ct * 16 + lr;
        bb[ct] = *(const h8*)&sB[r * 64 + ((((ks << 2) | quad) ^ (lr & 7)) << 3)];
      }
#pragma unroll
      for (int rt = 0; rt < 4; ++rt)
#pragma unroll
        for (int ct = 0; ct < 4; ++ct)
          acc[rt][ct] = MFMA16(a[rt], bb[ct], acc[rt][ct]);
    }
    __syncthreads();  // FREE
    if (kt < 7) {
#pragma unroll
      for (int j = 0; j < 4; ++j) {
        gl_lds16(Ab + (kt + 1) * 16384 + tid * 16 + j * 4096, (char*)sA + tid * 16 + j * 4096);
        gl_lds16(Bb + (kt + 1) * 16384 + tid * 16 + j * 4096, (char*)sB + tid * 16 + j * 4096);
      }
    }
  }

  // epilogue: fp16 stash in Simg layout -> coalesced stores
  _Float16* sC = sMem;
#pragma unroll
  for (int ct = 0; ct < 4; ++ct) {
    const int tl = cbase + ct * 16 + lr;
#pragma unroll
    for (int rt = 0; rt < 4; ++rt) {
#pragma unroll
      for (int r = 0; r < 4; ++r) {
        const int sl = rbase + rt * 16 + quad * 4 + r;
        sC[((tl >> 6) << 13) + sl * 64 + ((((tl >> 3) & 7) ^ (sl & 7)) << 3) + (tl & 7)] =
            (_Float16)acc[rt][ct][r];
      }
    }
  }
  __syncthreads();
  char* dst = S + ((size_t)(rbL * 64 + cb * 2 + (tid >> 7))) * 16384 + (size_t)(tid & 127) * 128;
#pragma unroll
  for (int k = 0; k < 8; ++k)
    *(int4*)(dst + k * 16) = *(const int4*)&sC[tid * 64 + k * 8];
}

// ---------------- ML: rowmax, P = exp(S-m) in place, linv ----------------
__global__ __launch_bounds__(256, 2)
void ml_kernel(char* __restrict__ S, float* __restrict__ linv, int b0, int s0, int msLog) {
  const int tid = threadIdx.x;
  const int wave = tid >> 6, lane = tid & 63;
  const int r = blockIdx.x * 4 + wave;  // chunk row
  const int rbL = r >> 7, rl = r & 127;
  char* base = S + ((size_t)(rbL * 64 + lane)) * 16384 + (size_t)rl * 128;
  h8 v[8];
#pragma unroll
  for (int k = 0; k < 8; ++k) v[k] = *(const h8*)(base + k * 16);
  float m = -3.0e38f;
#pragma unroll
  for (int k = 0; k < 8; ++k)
#pragma unroll
    for (int j = 0; j < 8; ++j) m = fmaxf(m, (float)v[k][j]);
  m = fmaxf(m, __shfl_xor(m, 1));
  m = fmaxf(m, __shfl_xor(m, 2));
  m = fmaxf(m, __shfl_xor(m, 4));
  m = fmaxf(m, __shfl_xor(m, 8));
  m = fmaxf(m, __shfl_xor(m, 16));
  m = fmaxf(m, __shfl_xor(m, 32));
  float s = 0.f;
#pragma unroll
  for (int k = 0; k < 8; ++k)
#pragma unroll
    for (int j = 0; j < 8; ++j) {
      float e = __expf((float)v[k][j] - m);
      v[k][j] = (_Float16)e;
      s += e;
    }
#pragma unroll
  for (int k = 0; k < 8; ++k) *(h8*)(base + k * 16) = v[k];
  s += __shfl_xor(s, 1);
  s += __shfl_xor(s, 2);
  s += __shfl_xor(s, 4);
  s += __shfl_xor(s, 8);
  s += __shfl_xor(s, 16);
  s += __shfl_xor(s, 32);
  if (lane == 0) {
    const int bL = r >> msLog, sloc = r & ((1 << msLog) - 1);
    linv[(b0 + bL) * 4096 + s0 + sloc] = 1.0f / s;
  }
}

// ---------------- PV GEMM: O[s][d] = P . V (64x128 tiles, K=4096) ----------------
__global__ __launch_bounds__(256, 4)
void pv_kernel(const char* __restrict__ S, const char* __restrict__ VTimg,
               const float* __restrict__ linv, float* __restrict__ out, int b0, int s0) {
  __shared__ _Float16 sMem[12288];  // sA 4096 (8KB) + sB 8192 (16KB)
  _Float16* sA = sMem;
  _Float16* sB = sMem + 4096;
  const int tid = threadIdx.x;
  const int wave = tid >> 6, lane = tid & 63;
  const int quad = lane >> 4, lr = lane & 15;
  const int db = blockIdx.x;                            // 0..3
  const int sbL = blockIdx.z * gridDim.y + blockIdx.y;  // chunk 64-row block
  const int b = b0 + blockIdx.z;
  const int rbase = (wave & 1) * 32, cbase = (wave >> 1) * 64;
  const char* Ab = S + ((size_t)((sbL >> 1) * 64)) * 16384 + (size_t)(sbL & 1) * 8192;
  const char* Bb = VTimg + ((size_t)((b * 4 + db) * 64)) * 16384;

  f4 acc[2][4];
#pragma unroll
  for (int i = 0; i < 2; ++i)
#pragma unroll
    for (int j = 0; j < 4; ++j) { f4 zz = {0.f, 0.f, 0.f, 0.f}; acc[i][j] = zz; }

  {  // stage(0)
#pragma unroll
    for (int j = 0; j < 2; ++j)
      gl_lds16(Ab + tid * 16 + j * 4096, (char*)sA + tid * 16 + j * 4096);
#pragma unroll
    for (int j = 0; j < 4; ++j)
      gl_lds16(Bb + tid * 16 + j * 4096, (char*)sB + tid * 16 + j * 4096);
  }

  for (int kt = 0; kt < 64; ++kt) {
    __syncthreads();  // DRAIN
#pragma unroll
    for (int ks = 0; ks < 2; ++ks) {
      h8 a[2], bb[4];
#pragma unroll
      for (int rt = 0; rt < 2; ++rt) {
        const int r = rbase + rt * 16 + lr;
        a[rt] = *(const h8*)&sA[r * 64 + ((((ks << 2) | quad) ^ (lr & 7)) << 3)];
      }
#pragma unroll
      for (int ct = 0; ct < 4; ++ct) {
        const int r = cbase + ct * 16 + lr;
        bb[ct] = *(const h8*)&sB[r * 64 + ((((ks << 2) | quad) ^ (lr & 7)) << 3)];
      }
#pragma unroll
      for (int rt = 0; rt < 2; ++rt)
#pragma unroll
        for (int ct = 0; ct < 4; ++ct)
          acc[rt][ct] = MFMA16(a[rt], bb[ct], acc[rt][ct]);
    }
    __syncthreads();  // FREE
    if (kt < 63) {
#pragma unroll
      for (int j = 0; j < 2; ++j)
        gl_lds16(Ab + (kt + 1) * 16384 + tid * 16 + j * 4096, (char*)sA + tid * 16 + j * 4096);
#pragma unroll
      for (int j = 0; j < 4; ++j)
        gl_lds16(Bb + (kt + 1) * 16384 + tid * 16 + j * 4096, (char*)sB + tid * 16 + j * 4096);
    }
  }

  // epilogue: x linv, scatter stores (64B segments per quad)
#pragma unroll
  for (int rt = 0; rt < 2; ++rt) {
#pragma unroll
    for (int r = 0; r < 4; ++r) {
      const int srow = s0 + blockIdx.y * 64 + rbase + rt * 16 + quad * 4 + r;
      const float li = linv[b * 4096 + srow];
      float* op = &out[((size_t)b * 4096 + srow) * 512 + db * 128];
#pragma unroll
      for (int ct = 0; ct < 4; ++ct)
        op[cbase + ct * 16 + lr] = acc[rt][ct][r] * li;
    }
  }
}

extern "C" void kernel_launch(void* const* d_in, const int* in_sizes, int n_in,
                              void* d_out, int out_size, void* d_ws, size_t ws_size,
                              hipStream_t stream) {
  (void)in_sizes; (void)n_in; (void)out_size;
  const float* x  = (const float*)d_in[0];
  const float* Wq = (const float*)d_in[1];
  const float* bq = (const float*)d_in[2];
  const float* Wk = (const float*)d_in[3];
  const float* bk = (const float*)d_in[4];
  const float* Wv = (const float*)d_in[5];
  const float* bv = (const float*)d_in[6];
  float* out = (float*)d_out;
  char* ws = (char*)d_ws;
  char* Qimg  = ws;
  char* Kimg  = ws + ((size_t)16 << 20);
  char* VTimg = ws + ((size_t)32 << 20);
  _Float16* Wt = (_Float16*)(ws + ((size_t)48 << 20));           // 1.5MB
  float* linv  = (float*)(ws + ((size_t)50 << 20) - 65536);      // 64KB
  char* Simg   = ws + ((size_t)50 << 20);

  wconv_kernel<<<dim3(384), dim3(256), 0, stream>>>(Wq, Wk, Wv, Wt);
  proj_kernel<<<dim3(128, 4, 3), dim3(256), 0, stream>>>(x, Wt, bq, bk, bv, Qimg, Kimg, VTimg);

  // chunk ladder on ws_size (constant per deployment -> same work every call)
  const size_t avail = ws_size > ((size_t)50 << 20) ? ws_size - ((size_t)50 << 20) : 0;
  int nchunk, nb, Ms;
  if      (avail >= ((size_t)128 << 20)) { nchunk = 1;  nb = 4; Ms = 4096; }
  else if (avail >= ((size_t)64  << 20)) { nchunk = 2;  nb = 2; Ms = 4096; }
  else if (avail >= ((size_t)32  << 20)) { nchunk = 4;  nb = 1; Ms = 4096; }
  else if (avail >= ((size_t)16  << 20)) { nchunk = 8;  nb = 1; Ms = 2048; }
  else if (avail >= ((size_t)8   << 20)) { nchunk = 16; nb = 1; Ms = 1024; }
  else                                   { nchunk = 32; nb = 1; Ms = 512;  }
  int msLog = 31 - __builtin_clz(Ms);
  const int chunksPerBatch = 4096 / Ms;  // for nb==1 paths; nb>1 has Ms=4096

  for (int c = 0; c < nchunk; ++c) {
    int b0, s0;
    if (nb > 1 || Ms == 4096) { b0 = c * nb; s0 = 0; }
    else { b0 = c / chunksPerBatch; s0 = (c % chunksPerBatch) * Ms; }
    qk_kernel<<<dim3(32, Ms / 128, nb), dim3(256), 0, stream>>>(Qimg, Kimg, Simg, b0, s0);
    ml_kernel<<<dim3(nb * Ms / 4), dim3(256), 0, stream>>>(Simg, linv, b0, s0, msLog);
    pv_kernel<<<dim3(4, Ms / 64, nb), dim3(256), 0, stream>>>(Simg, VTimg, linv, out, b0, s0);
  }
}